// Round 1
// baseline (466.995 us; speedup 1.0000x reference)
//
#include <hip/hip_runtime.h>
#include <stdint.h>

// ---------- types ----------
typedef __attribute__((ext_vector_type(8))) __bf16 bf16x8;
typedef __attribute__((ext_vector_type(4))) float f32x4;
typedef __attribute__((ext_vector_type(8))) unsigned short u16x8;

#define MFMA16(a, b, c) __builtin_amdgcn_mfma_f32_16x16x32_bf16((a), (b), (c), 0, 0, 0)

__device__ __forceinline__ void glds16(const void* g, void* l) {
  __builtin_amdgcn_global_load_lds(
      (const __attribute__((address_space(1))) void*)(uintptr_t)g,
      (__attribute__((address_space(3))) void*)(uint32_t)(uintptr_t)l,
      16, 0, 0);
}

__device__ __forceinline__ unsigned short f2bf(float f) {
  union { float f; unsigned u; } v; v.f = f;
  unsigned r = v.u + 0x7FFFu + ((v.u >> 16) & 1u);
  return (unsigned short)(r >> 16);
}
__device__ __forceinline__ float bf2f(unsigned short s) {
  union { unsigned u; float f; } v; v.u = ((unsigned)s) << 16;
  return v.f;
}

// ---------- problem constants ----------
#define B_ 32
#define N_ 512
#define C_ 1024
#define H_ 16
#define D_ 64
#define M_TOT (B_ * N_)      // 16384
#define N3C (3 * C_)         // 3072
#define K_ C_                // 1024

// ---------- tiny kernels ----------
__global__ __launch_bounds__(256) void rope_table_kernel(float* __restrict__ sin_t,
                                                         float* __restrict__ cos_t) {
  int idx = blockIdx.x * 256 + threadIdx.x;   // 0..16383 = n*32 + i
  int n = idx >> 5, i = idx & 31;
  float div = expf(-(2.0f * (float)i) * (9.210340371976184f / 64.0f));
  float ang = (float)n * div;
  sin_t[idx] = sinf(ang);
  cos_t[idx] = cosf(ang);
}

__global__ __launch_bounds__(256) void cvt_bf16_kernel(const float* __restrict__ in,
                                                       unsigned short* __restrict__ out,
                                                       int n8) {
  int i = blockIdx.x * blockDim.x + threadIdx.x;
  if (i >= n8) return;
  const float4* p = reinterpret_cast<const float4*>(in) + (size_t)i * 2;
  float4 a = p[0], b = p[1];
  u16x8 o;
  o[0] = f2bf(a.x); o[1] = f2bf(a.y); o[2] = f2bf(a.z); o[3] = f2bf(a.w);
  o[4] = f2bf(b.x); o[5] = f2bf(b.y); o[6] = f2bf(b.z); o[7] = f2bf(b.w);
  *reinterpret_cast<u16x8*>(out + (size_t)i * 8) = o;
}

// ---------- QKV GEMM (bf16 MFMA) with fused elu+rope epilogue ----------
// A = xb [16384][1024], B^T = wb [3072][1024]; C = A@B + bias
// writes: Qb,Kb [b,h,n,d] (rope(elu+1)) bf16 ; Vtb [b,h,d,n] bf16
__global__ __launch_bounds__(256, 2) void qkv_gemm_kernel(
    const unsigned short* __restrict__ xb, const unsigned short* __restrict__ wb,
    const float* __restrict__ bias,
    unsigned short* __restrict__ Qb, unsigned short* __restrict__ Kb,
    unsigned short* __restrict__ Vtb,
    const float* __restrict__ sin_t, const float* __restrict__ cos_t) {
  __shared__ unsigned short As[128 * 32];
  __shared__ unsigned short Bs[128 * 32];
  const int t = threadIdx.x;
  const int w = t >> 6, l = t & 63;
  const int m0 = blockIdx.y * 128, n0 = blockIdx.x * 128;
  const int wr = w >> 1, wc = w & 1;

  f32x4 acc[4][4] = {};

  const unsigned short* gA = xb + (size_t)(m0 + (t >> 2)) * K_ + (t & 3) * 8;
  const unsigned short* gB = wb + (size_t)(n0 + (t >> 2)) * K_ + (t & 3) * 8;

  for (int ks = 0; ks < 32; ++ks) {
    __syncthreads();
    glds16(gA + ks * 32, As + t * 8);                    // rows 0..63
    glds16(gA + 64 * K_ + ks * 32, As + 2048 + t * 8);   // rows 64..127
    glds16(gB + ks * 32, Bs + t * 8);
    glds16(gB + 64 * K_ + ks * 32, Bs + 2048 + t * 8);
    __syncthreads();
    bf16x8 af[4], bf[4];
#pragma unroll
    for (int i = 0; i < 4; i++)
      af[i] = *(const bf16x8*)(As + (wr * 64 + i * 16 + (l & 15)) * 32 + (l >> 4) * 8);
#pragma unroll
    for (int j = 0; j < 4; j++)
      bf[j] = *(const bf16x8*)(Bs + (wc * 64 + j * 16 + (l & 15)) * 32 + (l >> 4) * 8);
#pragma unroll
    for (int i = 0; i < 4; i++)
#pragma unroll
      for (int j = 0; j < 4; j++)
        acc[i][j] = MFMA16(af[i], bf[j], acc[i][j]);
  }

  // epilogue: D layout col=lane&15, row=(lane>>4)*4+reg
#pragma unroll
  for (int i = 0; i < 4; i++) {
#pragma unroll
    for (int j = 0; j < 4; j++) {
      const int ncol = n0 + wc * 64 + j * 16 + (l & 15);
      const int sel = ncol >> 10;            // uniform across wave (16-col blocks)
      const int hh = (ncol & 1023) >> 6;
      const int d = ncol & 63;
      const float bias_v = bias[ncol];
#pragma unroll
      for (int r = 0; r < 4; r++) {
        const int m = m0 + wr * 64 + i * 16 + (l >> 4) * 4 + r;
        const int bb = m >> 9, n = m & 511;
        const float val = acc[i][j][r] + bias_v;
        if (sel == 2) {
          Vtb[((size_t)(bb * H_ + hh) * D_ + d) * N_ + n] = f2bf(val);
        } else {
          const float e = val > 0.f ? val + 1.f : expf(val);  // elu+1
          const float partner = __shfl_xor(e, 1);
          const int ip = d >> 1;
          const float sv = sin_t[n * 32 + ip], cv = cos_t[n * 32 + ip];
          const float o = (d & 1) ? (partner * sv + e * cv) : (e * cv - partner * sv);
          unsigned short* dst = (sel == 0) ? Qb : Kb;
          dst[((size_t)(bb * H_ + hh) * N_ + n) * D_ + d] = f2bf(o);
        }
      }
    }
  }
}

// ---------- attention + lepe ----------
// grid: (8 qblocks, 512 bh); block 256 = 4 waves; each wave: 16 q rows.
// LDS: Ks [512][64] (XOR-swizzled chunks), Vs [64][512] (XOR-swizzled).
// P (per-wave 16x512) reuses Ks region after barrier.
__global__ __launch_bounds__(256, 1) void attn_kernel(
    const unsigned short* __restrict__ Qb, const unsigned short* __restrict__ Kb,
    const unsigned short* __restrict__ Vtb,
    const float* __restrict__ w_lepe, const float* __restrict__ b_lepe,
    float* __restrict__ out) {
  __shared__ unsigned short Ks[512 * 64];
  __shared__ unsigned short Vs[64 * 512];
  const int t = threadIdx.x, wv = t >> 6, l = t & 63;
  const int qb = blockIdx.x;           // 0..7
  const int bh = blockIdx.y;           // 0..511
  const int bb = bh >> 4, h = bh & 15;
  const size_t base = (size_t)bh * (N_ * D_);

  // stage K: rows r (k-index), 8 chunks of 16B per 128B row; source pre-swizzled
  {
    const int row = t >> 3, ch = t & 7;
#pragma unroll
    for (int c = 0; c < 16; ++c) {
      const int r = row + c * 32;
      const int sch = ch ^ (r & 7);
      glds16(Kb + base + (size_t)r * D_ + sch * 8, Ks + c * 2048 + t * 8);
    }
  }
  // stage Vt: rows d, 64 chunks per 1KB row
  {
    const int drow = t >> 6, ch = t & 63;
#pragma unroll
    for (int c = 0; c < 16; ++c) {
      const int r = drow + c * 4;
      const int sch = ch ^ (r & 7);
      glds16(Vtb + base + (size_t)r * N_ + sch * 8, Vs + c * 2048 + t * 8);
    }
  }
  // Q fragments (A-operand): row = l&15, k(d)-offset 8*(l>>4)
  const int ql = qb * 64 + wv * 16;
  const bf16x8 qf0 = *(const bf16x8*)(Qb + base + (size_t)(ql + (l & 15)) * D_ + (l >> 4) * 8);
  const bf16x8 qf1 = *(const bf16x8*)(Qb + base + (size_t)(ql + (l & 15)) * D_ + 32 + (l >> 4) * 8);
  __syncthreads();

  // S = Q @ K^T : 32 k-tiles of 16 cols
  f32x4 s[32];
#pragma unroll
  for (int kt = 0; kt < 32; ++kt) {
    const int r = kt * 16 + (l & 15);
    const int rx = r & 7;
    const unsigned short* kr = Ks + r * 64;
    const bf16x8 kf0 = *(const bf16x8*)(kr + (((l >> 4)) ^ rx) * 8);
    const bf16x8 kf1 = *(const bf16x8*)(kr + (((l >> 4) + 4) ^ rx) * 8);
    f32x4 a = {0.f, 0.f, 0.f, 0.f};
    a = MFMA16(qf0, kf0, a);
    a = MFMA16(qf1, kf1, a);
    s[kt] = a;
  }

  // wave-parallel softmax: per reg r, row = 4*(l>>4)+r; reduce over kt + 16 col-lanes
  const float scale = 0.125f;
  float inv[4];
#pragma unroll
  for (int r = 0; r < 4; r++) {
    float m = -1e30f;
#pragma unroll
    for (int kt = 0; kt < 32; kt++) m = fmaxf(m, s[kt][r]);
    m = fmaxf(m, __shfl_xor(m, 1));
    m = fmaxf(m, __shfl_xor(m, 2));
    m = fmaxf(m, __shfl_xor(m, 4));
    m = fmaxf(m, __shfl_xor(m, 8));
    float su = 0.f;
#pragma unroll
    for (int kt = 0; kt < 32; kt++) {
      const float p = expf((s[kt][r] - m) * scale);
      s[kt][r] = p;
      su += p;
    }
    su += __shfl_xor(su, 1);
    su += __shfl_xor(su, 2);
    su += __shfl_xor(su, 4);
    su += __shfl_xor(su, 8);
    inv[r] = 1.0f / su;
  }

  __syncthreads();  // everyone done reading Ks -> reuse as P
  unsigned short* Pw = Ks + wv * 8192;  // [16][512], rows q, swizzled chunks
#pragma unroll
  for (int kt = 0; kt < 32; kt++) {
    const int k = kt * 16 + (l & 15);
    const int ch = k >> 3, wi = k & 7;
#pragma unroll
    for (int r = 0; r < 4; r++) {
      const int q = (l >> 4) * 4 + r;
      Pw[q * 512 + ((ch ^ (q & 7)) << 3) + wi] = f2bf(s[kt][r] * inv[r]);
    }
  }

  // O = P @ V : 16 k-steps of 32
  f32x4 o[4] = {};
#pragma unroll
  for (int kk = 0; kk < 16; kk++) {
    const int q = l & 15;
    const bf16x8 pf = *(const bf16x8*)(Pw + q * 512 + (((kk * 4 + (l >> 4)) ^ (q & 7)) << 3));
#pragma unroll
    for (int j2 = 0; j2 < 4; j2++) {
      const int dr = j2 * 16 + (l & 15);
      const bf16x8 vf = *(const bf16x8*)(Vs + dr * 512 + (((kk * 4 + (l >> 4)) ^ (dr & 7)) << 3));
      o[j2] = MFMA16(pf, vf, o[j2]);
    }
  }

  // epilogue: + lepe (depthwise conv3 over n, from resident Vs) ; write fp32
#pragma unroll
  for (int j2 = 0; j2 < 4; j2++) {
    const int d = j2 * 16 + (l & 15);
    const int c = h * 64 + d;
    const float w0 = w_lepe[c * 3 + 0], w1 = w_lepe[c * 3 + 1], w2 = w_lepe[c * 3 + 2];
    const float bl = b_lepe[c];
#pragma unroll
    for (int r = 0; r < 4; r++) {
      const int q = (l >> 4) * 4 + r;
      const int n = qb * 64 + wv * 16 + q;
      const int dx = d & 7;
      float vm1 = 0.f, vp1 = 0.f;
      if (n > 0) {
        const int nn = n - 1;
        vm1 = bf2f(Vs[d * 512 + (((nn >> 3) ^ dx) << 3) + (nn & 7)]);
      }
      const float v0 = bf2f(Vs[d * 512 + (((n >> 3) ^ dx) << 3) + (n & 7)]);
      if (n < 511) {
        const int nn = n + 1;
        vp1 = bf2f(Vs[d * 512 + (((nn >> 3) ^ dx) << 3) + (nn & 7)]);
      }
      const float lepe = vm1 * w0 + v0 * w1 + vp1 * w2 + bl;
      out[((size_t)(bb * N_ + n)) * C_ + c] = o[j2][r] + lepe;
    }
  }
}

// ---------- launcher ----------
extern "C" void kernel_launch(void* const* d_in, const int* in_sizes, int n_in,
                              void* d_out, int out_size, void* d_ws, size_t ws_size,
                              hipStream_t stream) {
  (void)in_sizes; (void)n_in; (void)out_size; (void)ws_size;
  const float* x = (const float*)d_in[0];
  const float* w_qkv = (const float*)d_in[1];
  const float* b_qkv = (const float*)d_in[2];
  const float* w_lepe = (const float*)d_in[3];
  const float* b_lepe = (const float*)d_in[4];
  float* out = (float*)d_out;

  unsigned short* ws = (unsigned short*)d_ws;
  unsigned short* xb = ws;                          // 16777216 el
  unsigned short* wb = xb + 16777216;               // 3145728 el
  unsigned short* Qb = wb + 3145728;                // 16777216 el
  unsigned short* Kb = Qb + 16777216;               // 16777216 el
  unsigned short* Vtb = Kb + 16777216;              // 16777216 el
  float* sin_t = (float*)(Vtb + 16777216);          // 16384 f32
  float* cos_t = sin_t + 16384;                     // 16384 f32

  rope_table_kernel<<<64, 256, 0, stream>>>(sin_t, cos_t);
  cvt_bf16_kernel<<<(16777216 / 8 + 255) / 256, 256, 0, stream>>>(x, xb, 16777216 / 8);
  cvt_bf16_kernel<<<(3145728 / 8 + 255) / 256, 256, 0, stream>>>(w_qkv, wb, 3145728 / 8);
  qkv_gemm_kernel<<<dim3(24, 128), 256, 0, stream>>>(xb, wb, b_qkv, Qb, Kb, Vtb, sin_t, cos_t);
  attn_kernel<<<dim3(8, 512), 256, 0, stream>>>(Qb, Kb, Vtb, w_lepe, b_lepe, out);
}

// Round 2
// 337.642 us; speedup vs baseline: 1.3831x; 1.3831x over previous
//
#include <hip/hip_runtime.h>
#include <stdint.h>

// ---------- types ----------
typedef __attribute__((ext_vector_type(8))) __bf16 bf16x8;
typedef __attribute__((ext_vector_type(4))) float f32x4;
typedef __attribute__((ext_vector_type(8))) unsigned short u16x8;

#define MFMA16(a, b, c) __builtin_amdgcn_mfma_f32_16x16x32_bf16((a), (b), (c), 0, 0, 0)

__device__ __forceinline__ void glds16(const void* g, void* l) {
  __builtin_amdgcn_global_load_lds(
      (const __attribute__((address_space(1))) void*)(uintptr_t)g,
      (__attribute__((address_space(3))) void*)(uint32_t)(uintptr_t)l,
      16, 0, 0);
}

__device__ __forceinline__ unsigned short f2bf(float f) {
  union { float f; unsigned u; } v; v.f = f;
  unsigned r = v.u + 0x7FFFu + ((v.u >> 16) & 1u);
  return (unsigned short)(r >> 16);
}
__device__ __forceinline__ float bf2f(unsigned short s) {
  union { unsigned u; float f; } v; v.u = ((unsigned)s) << 16;
  return v.f;
}

// ---------- problem constants ----------
#define B_ 32
#define N_ 512
#define C_ 1024
#define H_ 16
#define D_ 64
#define K_ C_                // 1024

// ---------- tiny kernels ----------
__global__ __launch_bounds__(256) void rope_table_kernel(float* __restrict__ sin_t,
                                                         float* __restrict__ cos_t) {
  int idx = blockIdx.x * 256 + threadIdx.x;   // 0..16383 = n*32 + i
  int n = idx >> 5, i = idx & 31;
  float div = expf(-(2.0f * (float)i) * (9.210340371976184f / 64.0f));
  float ang = (float)n * div;
  sin_t[idx] = sinf(ang);
  cos_t[idx] = cosf(ang);
}

__global__ __launch_bounds__(256) void cvt_bf16_kernel(const float* __restrict__ in,
                                                       unsigned short* __restrict__ out,
                                                       int n8) {
  int i = blockIdx.x * blockDim.x + threadIdx.x;
  if (i >= n8) return;
  const float4* p = reinterpret_cast<const float4*>(in) + (size_t)i * 2;
  float4 a = p[0], b = p[1];
  u16x8 o;
  o[0] = f2bf(a.x); o[1] = f2bf(a.y); o[2] = f2bf(a.z); o[3] = f2bf(a.w);
  o[4] = f2bf(b.x); o[5] = f2bf(b.y); o[6] = f2bf(b.z); o[7] = f2bf(b.w);
  *reinterpret_cast<u16x8*>(out + (size_t)i * 8) = o;
}

// ---------- QKV GEMM (bf16 MFMA) with fused elu+rope epilogue ----------
__global__ __launch_bounds__(256, 2) void qkv_gemm_kernel(
    const unsigned short* __restrict__ xb, const unsigned short* __restrict__ wb,
    const float* __restrict__ bias,
    unsigned short* __restrict__ Qb, unsigned short* __restrict__ Kb,
    unsigned short* __restrict__ Vtb,
    const float* __restrict__ sin_t, const float* __restrict__ cos_t) {
  __shared__ unsigned short As[128 * 32];
  __shared__ unsigned short Bs[128 * 32];
  const int t = threadIdx.x;
  const int w = t >> 6, l = t & 63;
  const int m0 = blockIdx.y * 128, n0 = blockIdx.x * 128;
  const int wr = w >> 1, wc = w & 1;

  f32x4 acc[4][4] = {};

  const unsigned short* gA = xb + (size_t)(m0 + (t >> 2)) * K_ + (t & 3) * 8;
  const unsigned short* gB = wb + (size_t)(n0 + (t >> 2)) * K_ + (t & 3) * 8;

  for (int ks = 0; ks < 32; ++ks) {
    __syncthreads();
    glds16(gA + ks * 32, As + t * 8);
    glds16(gA + 64 * K_ + ks * 32, As + 2048 + t * 8);
    glds16(gB + ks * 32, Bs + t * 8);
    glds16(gB + 64 * K_ + ks * 32, Bs + 2048 + t * 8);
    __syncthreads();
    bf16x8 af[4], bf[4];
#pragma unroll
    for (int i = 0; i < 4; i++)
      af[i] = *(const bf16x8*)(As + (wr * 64 + i * 16 + (l & 15)) * 32 + (l >> 4) * 8);
#pragma unroll
    for (int j = 0; j < 4; j++)
      bf[j] = *(const bf16x8*)(Bs + (wc * 64 + j * 16 + (l & 15)) * 32 + (l >> 4) * 8);
#pragma unroll
    for (int i = 0; i < 4; i++)
#pragma unroll
      for (int j = 0; j < 4; j++)
        acc[i][j] = MFMA16(af[i], bf[j], acc[i][j]);
  }

#pragma unroll
  for (int i = 0; i < 4; i++) {
#pragma unroll
    for (int j = 0; j < 4; j++) {
      const int ncol = n0 + wc * 64 + j * 16 + (l & 15);
      const int sel = ncol >> 10;
      const int hh = (ncol & 1023) >> 6;
      const int d = ncol & 63;
      const float bias_v = bias[ncol];
#pragma unroll
      for (int r = 0; r < 4; r++) {
        const int m = m0 + wr * 64 + i * 16 + (l >> 4) * 4 + r;
        const int bb = m >> 9, n = m & 511;
        const float val = acc[i][j][r] + bias_v;
        if (sel == 2) {
          Vtb[((size_t)(bb * H_ + hh) * D_ + d) * N_ + n] = f2bf(val);
        } else {
          const float e = val > 0.f ? val + 1.f : expf(val);  // elu+1
          const float partner = __shfl_xor(e, 1);
          const int ip = d >> 1;
          const float sv = sin_t[n * 32 + ip], cv = cos_t[n * 32 + ip];
          const float o = (d & 1) ? (partner * sv + e * cv) : (e * cv - partner * sv);
          unsigned short* dst = (sel == 0) ? Qb : Kb;
          dst[((size_t)(bb * H_ + hh) * N_ + n) * D_ + d] = f2bf(o);
        }
      }
    }
  }
}

// ---------- attention + lepe : one block per (b,h) ----------
// block 512 = 8 waves; each wave handles 64 q rows (4 tiles of 16).
// LDS: Ks [512][64] (swizzled) 64KB, Vs [64][512] (swizzled) 64KB,
//      Pb 8 waves x [16][128] (swizzled, k-chunked x4) 32KB. Total 160KB.
__global__ __launch_bounds__(512, 2) void attn_kernel(
    const unsigned short* __restrict__ Qb, const unsigned short* __restrict__ Kb,
    const unsigned short* __restrict__ Vtb,
    const float* __restrict__ w_lepe, const float* __restrict__ b_lepe,
    float* __restrict__ out) {
  __shared__ unsigned short Ks[512 * 64];
  __shared__ unsigned short Vs[64 * 512];
  __shared__ unsigned short Pb[8 * 16 * 128];
  const int t = threadIdx.x, wv = t >> 6, l = t & 63;
  const int bh = blockIdx.x;           // 0..511
  const int bb = bh >> 4, h = bh & 15;
  const size_t base = (size_t)bh * (N_ * D_);

  // stage K: 8 iters, 512 thr x 16B; dest linear, source chunk pre-swizzled
  {
    const int row8 = t >> 3, ch = t & 7;
#pragma unroll
    for (int c = 0; c < 8; ++c) {
      const int r = c * 64 + row8;
      const int sch = ch ^ (r & 7);
      glds16(Kb + base + (size_t)r * D_ + sch * 8, Ks + c * 4096 + t * 8);
    }
  }
  // stage Vt: 8 iters; wave w stages row d = c*8+w (1KB per wave-iter)
  {
    const int ch = t & 63;
#pragma unroll
    for (int c = 0; c < 8; ++c) {
      const int d = c * 8 + wv;
      const int sch = ch ^ (d & 7);
      glds16(Vtb + base + (size_t)d * N_ + sch * 8, Vs + c * 4096 + t * 8);
    }
  }

  // wait K only (oldest 8 of 16 outstanding per lane), keep V in flight
  asm volatile("s_waitcnt vmcnt(8)" ::: "memory");
  __builtin_amdgcn_s_barrier();

  const float scale = 0.125f;  // 1/sqrt(64)
  unsigned short* Pw = Pb + wv * 2048;  // [16][128] halfwords, 16B-slot swizzle

  for (int p = 0; p < 4; ++p) {
    const int ql = wv * 64 + p * 16;
    const bf16x8 qf0 = *(const bf16x8*)(Qb + base + (size_t)(ql + (l & 15)) * D_ + (l >> 4) * 8);
    const bf16x8 qf1 = *(const bf16x8*)(Qb + base + (size_t)(ql + (l & 15)) * D_ + 32 + (l >> 4) * 8);

    // S = Q @ K^T : 32 col-tiles of 16
    f32x4 s[32];
#pragma unroll
    for (int kt = 0; kt < 32; ++kt) {
      const int r = kt * 16 + (l & 15);
      const int rx = r & 7;
      const unsigned short* kr = Ks + r * 64;
      const bf16x8 kf0 = *(const bf16x8*)(kr + (((l >> 4)) ^ rx) * 8);
      const bf16x8 kf1 = *(const bf16x8*)(kr + (((l >> 4) + 4) ^ rx) * 8);
      f32x4 a = {0.f, 0.f, 0.f, 0.f};
      a = MFMA16(qf0, kf0, a);
      a = MFMA16(qf1, kf1, a);
      s[kt] = a;
    }

    // wave-parallel softmax: row q=(l>>4)*4+r; reduce over 32 kt + 16 col-lanes
    float inv[4];
#pragma unroll
    for (int r = 0; r < 4; r++) {
      float m = -1e30f;
#pragma unroll
      for (int kt = 0; kt < 32; kt++) m = fmaxf(m, s[kt][r]);
      m = fmaxf(m, __shfl_xor(m, 1));
      m = fmaxf(m, __shfl_xor(m, 2));
      m = fmaxf(m, __shfl_xor(m, 4));
      m = fmaxf(m, __shfl_xor(m, 8));
      float su = 0.f;
#pragma unroll
      for (int kt = 0; kt < 32; kt++) {
        const float pv = expf((s[kt][r] - m) * scale);
        s[kt][r] = pv;
        su += pv;
      }
      su += __shfl_xor(su, 1);
      su += __shfl_xor(su, 2);
      su += __shfl_xor(su, 4);
      su += __shfl_xor(su, 8);
      inv[r] = 1.0f / su;
    }

    if (p == 0) __syncthreads();  // V staged (drains vmcnt(0)); reached by all waves once

    // PV in 4 k-chunks of 128 through per-wave P buffer (no block sync needed)
    f32x4 o[4] = {};
#pragma unroll
    for (int cc = 0; cc < 4; ++cc) {
      // write P chunk: rows q, 128 k-locals, 16B slots XOR q&7
#pragma unroll
      for (int kl = 0; kl < 8; ++kl) {
        const int klocal = kl * 16 + (l & 15);
        const int slot = klocal >> 3;
#pragma unroll
        for (int r = 0; r < 4; ++r) {
          const int q = (l >> 4) * 4 + r;
          Pw[q * 128 + ((slot ^ (q & 7)) << 3) + (klocal & 7)] =
              f2bf(s[cc * 8 + kl][r] * inv[r]);
        }
      }
      // PV: 4 k-steps of 32 within the chunk
#pragma unroll
      for (int ks = 0; ks < 4; ++ks) {
        const int q = l & 15;
        const bf16x8 pf =
            *(const bf16x8*)(Pw + q * 128 + (((ks * 4 + (l >> 4)) ^ (q & 7)) << 3));
        const int ci = cc * 16 + ks * 4 + (l >> 4);
#pragma unroll
        for (int j2 = 0; j2 < 4; j2++) {
          const int dr = j2 * 16 + (l & 15);
          const bf16x8 vf = *(const bf16x8*)(Vs + dr * 512 + ((ci ^ (dr & 7)) << 3));
          o[j2] = MFMA16(pf, vf, o[j2]);
        }
      }
    }

    // epilogue: + lepe (depthwise conv3 over n from resident Vs); write fp32
#pragma unroll
    for (int j2 = 0; j2 < 4; j2++) {
      const int d = j2 * 16 + (l & 15);
      const int c = h * 64 + d;
      const float w0 = w_lepe[c * 3 + 0], w1 = w_lepe[c * 3 + 1], w2 = w_lepe[c * 3 + 2];
      const float bl = b_lepe[c];
      const int dx = d & 7;
#pragma unroll
      for (int r = 0; r < 4; r++) {
        const int q = (l >> 4) * 4 + r;
        const int n = ql + q;
        float vm1 = 0.f, vp1 = 0.f;
        if (n > 0) {
          const int nn = n - 1;
          vm1 = bf2f(Vs[d * 512 + (((nn >> 3) ^ dx) << 3) + (nn & 7)]);
        }
        const float v0 = bf2f(Vs[d * 512 + (((n >> 3) ^ dx) << 3) + (n & 7)]);
        if (n < 511) {
          const int nn = n + 1;
          vp1 = bf2f(Vs[d * 512 + (((nn >> 3) ^ dx) << 3) + (nn & 7)]);
        }
        const float lepe = vm1 * w0 + v0 * w1 + vp1 * w2 + bl;
        out[((size_t)(bb * N_ + n)) * C_ + c] = o[j2][r] + lepe;
      }
    }
  }
}

// ---------- launcher ----------
extern "C" void kernel_launch(void* const* d_in, const int* in_sizes, int n_in,
                              void* d_out, int out_size, void* d_ws, size_t ws_size,
                              hipStream_t stream) {
  (void)in_sizes; (void)n_in; (void)out_size; (void)ws_size;
  const float* x = (const float*)d_in[0];
  const float* w_qkv = (const float*)d_in[1];
  const float* b_qkv = (const float*)d_in[2];
  const float* w_lepe = (const float*)d_in[3];
  const float* b_lepe = (const float*)d_in[4];
  float* out = (float*)d_out;

  unsigned short* ws = (unsigned short*)d_ws;
  unsigned short* xb = ws;                          // 16777216 el
  unsigned short* wb = xb + 16777216;               // 3145728 el
  unsigned short* Qb = wb + 3145728;                // 16777216 el
  unsigned short* Kb = Qb + 16777216;               // 16777216 el
  unsigned short* Vtb = Kb + 16777216;              // 16777216 el
  float* sin_t = (float*)(Vtb + 16777216);          // 16384 f32
  float* cos_t = sin_t + 16384;                     // 16384 f32

  rope_table_kernel<<<64, 256, 0, stream>>>(sin_t, cos_t);
  cvt_bf16_kernel<<<(16777216 / 8 + 255) / 256, 256, 0, stream>>>(x, xb, 16777216 / 8);
  cvt_bf16_kernel<<<(3145728 / 8 + 255) / 256, 256, 0, stream>>>(w_qkv, wb, 3145728 / 8);
  qkv_gemm_kernel<<<dim3(24, 128), 256, 0, stream>>>(xb, wb, b_qkv, Qb, Kb, Vtb, sin_t, cos_t);
  attn_kernel<<<512, 512, 0, stream>>>(Qb, Kb, Vtb, w_lepe, b_lepe, out);
}

// Round 3
// 323.489 us; speedup vs baseline: 1.4436x; 1.0437x over previous
//
#include <hip/hip_runtime.h>
#include <stdint.h>

// ---------- types ----------
typedef __attribute__((ext_vector_type(8))) __bf16 bf16x8;
typedef __attribute__((ext_vector_type(4))) float f32x4;
typedef __attribute__((ext_vector_type(8))) unsigned short u16x8;

#define MFMA16(a, b, c) __builtin_amdgcn_mfma_f32_16x16x32_bf16((a), (b), (c), 0, 0, 0)

__device__ __forceinline__ void glds16(const void* g, void* l) {
  __builtin_amdgcn_global_load_lds(
      (const __attribute__((address_space(1))) void*)(uintptr_t)g,
      (__attribute__((address_space(3))) void*)(uint32_t)(uintptr_t)l,
      16, 0, 0);
}

__device__ __forceinline__ unsigned short f2bf(float f) {
  union { float f; unsigned u; } v; v.f = f;
  unsigned r = v.u + 0x7FFFu + ((v.u >> 16) & 1u);
  return (unsigned short)(r >> 16);
}
__device__ __forceinline__ float bf2f(unsigned short s) {
  union { unsigned u; float f; } v; v.u = ((unsigned)s) << 16;
  return v.f;
}

// ---------- problem constants ----------
#define B_ 32
#define N_ 512
#define C_ 1024
#define H_ 16
#define D_ 64
#define K_ C_                // 1024

// ---------- tiny kernels ----------
__global__ __launch_bounds__(256) void rope_table_kernel(float* __restrict__ sin_t,
                                                         float* __restrict__ cos_t) {
  int idx = blockIdx.x * 256 + threadIdx.x;   // 0..16383 = n*32 + i
  int n = idx >> 5, i = idx & 31;
  float div = expf(-(2.0f * (float)i) * (9.210340371976184f / 64.0f));
  float ang = (float)n * div;
  sin_t[idx] = sinf(ang);
  cos_t[idx] = cosf(ang);
}

__global__ __launch_bounds__(256) void cvt_bf16_kernel(const float* __restrict__ in,
                                                       unsigned short* __restrict__ out,
                                                       int n8) {
  int i = blockIdx.x * blockDim.x + threadIdx.x;
  if (i >= n8) return;
  const float4* p = reinterpret_cast<const float4*>(in) + (size_t)i * 2;
  float4 a = p[0], b = p[1];
  u16x8 o;
  o[0] = f2bf(a.x); o[1] = f2bf(a.y); o[2] = f2bf(a.z); o[3] = f2bf(a.w);
  o[4] = f2bf(b.x); o[5] = f2bf(b.y); o[6] = f2bf(b.z); o[7] = f2bf(b.w);
  *reinterpret_cast<u16x8*>(out + (size_t)i * 8) = o;
}

// ---------- QKV GEMM: 256x256 tile, BK=64, 8-phase counted-vmcnt schedule ----------
// A = xb [16384][1024], B^T = wb [3072][1024].
// LDS per buffer: A [256][64] hw (chunk^=row&7 swizzled), B [256][64]. 2 buffers = 128KB.
// 8 waves (2 M x 4 N); wave output 128x64 = acc[8][4].
// Per K-tile (4 phases): ph0 reads all B-frags + A mf{0,1}, stages A1(u+1);
// ph p reads A mf{2p,2p+1}, stages {B0,B1,A0}(u+2). vmcnt(6) once per tile.
#define STAGE_A(bi, kt, h)                                                        \
  do {                                                                            \
    glds16(aSrc[(h)*2 + 0] + (size_t)(kt) * 64, &lds[bi][(h)*8192 + t * 8]);      \
    glds16(aSrc[(h)*2 + 1] + (size_t)(kt) * 64, &lds[bi][(h)*8192 + 4096 + t * 8]); \
  } while (0)
#define STAGE_B(bi, kt, h)                                                        \
  do {                                                                            \
    glds16(bSrc[(h)*2 + 0] + (size_t)(kt) * 64, &lds[bi][16384 + (h)*8192 + t * 8]); \
    glds16(bSrc[(h)*2 + 1] + (size_t)(kt) * 64,                                   \
           &lds[bi][16384 + (h)*8192 + 4096 + t * 8]);                            \
  } while (0)

__global__ __launch_bounds__(512, 2) void qkv_gemm_kernel(
    const unsigned short* __restrict__ xb, const unsigned short* __restrict__ wb,
    const float* __restrict__ bias,
    unsigned short* __restrict__ Qb, unsigned short* __restrict__ Kb,
    unsigned short* __restrict__ Vtb,
    const float* __restrict__ sin_t, const float* __restrict__ cos_t) {
  __shared__ unsigned short lds[2][32768];  // 128 KB
  const int t = threadIdx.x;
  const int wv = t >> 6, l = t & 63;
  const int wr = wv >> 2, wc = wv & 3;   // 2 x 4 waves
  const int lq = l >> 4, lr = l & 15, sx = l & 7;

  // XCD-chunked bijective swizzle (768 % 8 == 0)
  const int bid = (blockIdx.x & 7) * 96 + (blockIdx.x >> 3);
  const int mBlk = bid / 12, nBlk = bid % 12;
  const int m0 = mBlk * 256, n0 = nBlk * 256;

  // staging source pointers (global chunk pre-swizzled; LDS dest linear)
  const int rl = t >> 3;                       // 0..63
  const int cw = ((t & 7) ^ (rl & 7)) * 8;     // swizzled source chunk (halfwords)
  const unsigned short* aSrc[4];
  const unsigned short* bSrc[4];
#pragma unroll
  for (int h = 0; h < 2; ++h)
#pragma unroll
    for (int c = 0; c < 2; ++c) {
      aSrc[h * 2 + c] = xb + (size_t)(m0 + h * 128 + c * 64 + rl) * K_ + cw;
      bSrc[h * 2 + c] = wb + (size_t)(n0 + h * 128 + c * 64 + rl) * K_ + cw;
    }

  // fragment read offsets (halfwords), + mf*1024 / + j*1024
  int aoff[2], boff[2];
#pragma unroll
  for (int s = 0; s < 2; ++s) {
    const int ch = ((s * 4 + lq) ^ sx) * 8;
    aoff[s] = (wr * 128 + lr) * 64 + ch;
    boff[s] = 16384 + (wc * 64 + lr) * 64 + ch;
  }

  f32x4 acc[8][4] = {};

  // prologue: tile 0 fully, tile 1 minus A1  (14 loads/thread-wave pattern)
  STAGE_B(0, 0, 0); STAGE_B(0, 0, 1); STAGE_A(0, 0, 0); STAGE_A(0, 0, 1);
  STAGE_B(1, 1, 0); STAGE_B(1, 1, 1); STAGE_A(1, 1, 0);

  for (int u = 0; u < 16; ++u) {
    const int cur = u & 1, nxt = cur ^ 1;
    const unsigned short* Lc = &lds[cur][0];
    if (u == 15) asm volatile("s_waitcnt vmcnt(0)" ::: "memory");
    else         asm volatile("s_waitcnt vmcnt(6)" ::: "memory");
    __builtin_amdgcn_s_barrier();

    // ---- phase 0: all B-frags + A mf{0,1}; stage A1(u+1) ----
    bf16x8 bfr[4][2];
#pragma unroll
    for (int j = 0; j < 4; ++j)
#pragma unroll
      for (int s = 0; s < 2; ++s)
        bfr[j][s] = *(const bf16x8*)(Lc + boff[s] + j * 1024);
    {
      bf16x8 afr[2][2];
#pragma unroll
      for (int mm = 0; mm < 2; ++mm)
#pragma unroll
        for (int s = 0; s < 2; ++s)
          afr[mm][s] = *(const bf16x8*)(Lc + aoff[s] + mm * 1024);
      if (u + 1 < 16) STAGE_A(nxt, u + 1, 1);
      asm volatile("s_waitcnt lgkmcnt(8)" ::: "memory");
      __builtin_amdgcn_s_barrier();
      asm volatile("s_waitcnt lgkmcnt(0)" ::: "memory");
      __builtin_amdgcn_s_setprio(1);
#pragma unroll
      for (int mm = 0; mm < 2; ++mm)
#pragma unroll
        for (int j = 0; j < 4; ++j)
#pragma unroll
          for (int s = 0; s < 2; ++s)
            acc[mm][j] = MFMA16(afr[mm][s], bfr[j][s], acc[mm][j]);
      __builtin_amdgcn_s_setprio(0);
      __builtin_amdgcn_s_barrier();
    }

    // ---- phases 1..3: A mf{2p,2p+1}; stage B0/B1/A0 (u+2) ----
#pragma unroll
    for (int p = 1; p < 4; ++p) {
      bf16x8 afr[2][2];
#pragma unroll
      for (int mm = 0; mm < 2; ++mm)
#pragma unroll
        for (int s = 0; s < 2; ++s)
          afr[mm][s] = *(const bf16x8*)(Lc + aoff[s] + (2 * p + mm) * 1024);
      if (u + 2 < 16) {
        if (p == 1)      STAGE_B(cur, u + 2, 0);
        else if (p == 2) STAGE_B(cur, u + 2, 1);
        else             STAGE_A(cur, u + 2, 0);
      }
      __builtin_amdgcn_s_barrier();
      asm volatile("s_waitcnt lgkmcnt(0)" ::: "memory");
      __builtin_amdgcn_s_setprio(1);
#pragma unroll
      for (int mm = 0; mm < 2; ++mm)
#pragma unroll
        for (int j = 0; j < 4; ++j)
#pragma unroll
          for (int s = 0; s < 2; ++s)
            acc[2 * p + mm][j] = MFMA16(afr[mm][s], bfr[j][s], acc[2 * p + mm][j]);
      __builtin_amdgcn_s_setprio(0);
      if (p < 3) __builtin_amdgcn_s_barrier();
    }
  }

  // ---- fused epilogue: bias + (elu+1, rope -> Qb/Kb) or (V -> Vtb transposed) ----
#pragma unroll
  for (int mf = 0; mf < 8; ++mf) {
#pragma unroll
    for (int j = 0; j < 4; ++j) {
      const int ncol = n0 + wc * 64 + j * 16 + lr;
      const int sel = ncol >> 10;
      const int hh = (ncol & 1023) >> 6;
      const int d = ncol & 63;
      const float bias_v = bias[ncol];
#pragma unroll
      for (int r = 0; r < 4; ++r) {
        const int m = m0 + wr * 128 + mf * 16 + lq * 4 + r;
        const int bb = m >> 9, n = m & 511;
        const float val = acc[mf][j][r] + bias_v;
        if (sel == 2) {
          Vtb[((size_t)(bb * H_ + hh) * D_ + d) * N_ + n] = f2bf(val);
        } else {
          const float e = val > 0.f ? val + 1.f : expf(val);  // elu+1
          const float partner = __shfl_xor(e, 1);
          const int ip = d >> 1;
          const float sv = sin_t[n * 32 + ip], cv = cos_t[n * 32 + ip];
          const float o = (d & 1) ? (partner * sv + e * cv) : (e * cv - partner * sv);
          unsigned short* dst = (sel == 0) ? Qb : Kb;
          dst[((size_t)(bb * H_ + hh) * N_ + n) * D_ + d] = f2bf(o);
        }
      }
    }
  }
}

// ---------- attention + lepe : one block per (b,h) ----------
__global__ __launch_bounds__(512, 2) void attn_kernel(
    const unsigned short* __restrict__ Qb, const unsigned short* __restrict__ Kb,
    const unsigned short* __restrict__ Vtb,
    const float* __restrict__ w_lepe, const float* __restrict__ b_lepe,
    float* __restrict__ out) {
  __shared__ unsigned short Ks[512 * 64];
  __shared__ unsigned short Vs[64 * 512];
  __shared__ unsigned short Pb[8 * 16 * 128];
  const int t = threadIdx.x, wv = t >> 6, l = t & 63;
  const int bh = blockIdx.x;           // 0..511
  const int bb = bh >> 4, h = bh & 15;
  const size_t base = (size_t)bh * (N_ * D_);

  {
    const int row8 = t >> 3, ch = t & 7;
#pragma unroll
    for (int c = 0; c < 8; ++c) {
      const int r = c * 64 + row8;
      const int sch = ch ^ (r & 7);
      glds16(Kb + base + (size_t)r * D_ + sch * 8, Ks + c * 4096 + t * 8);
    }
  }
  {
    const int ch = t & 63;
#pragma unroll
    for (int c = 0; c < 8; ++c) {
      const int d = c * 8 + wv;
      const int sch = ch ^ (d & 7);
      glds16(Vtb + base + (size_t)d * N_ + sch * 8, Vs + c * 4096 + t * 8);
    }
  }

  asm volatile("s_waitcnt vmcnt(8)" ::: "memory");
  __builtin_amdgcn_s_barrier();

  const float scale = 0.125f;  // 1/sqrt(64)
  unsigned short* Pw = Pb + wv * 2048;

  for (int p = 0; p < 4; ++p) {
    const int ql = wv * 64 + p * 16;
    const bf16x8 qf0 = *(const bf16x8*)(Qb + base + (size_t)(ql + (l & 15)) * D_ + (l >> 4) * 8);
    const bf16x8 qf1 = *(const bf16x8*)(Qb + base + (size_t)(ql + (l & 15)) * D_ + 32 + (l >> 4) * 8);

    f32x4 s[32];
#pragma unroll
    for (int kt = 0; kt < 32; ++kt) {
      const int r = kt * 16 + (l & 15);
      const int rx = r & 7;
      const unsigned short* kr = Ks + r * 64;
      const bf16x8 kf0 = *(const bf16x8*)(kr + (((l >> 4)) ^ rx) * 8);
      const bf16x8 kf1 = *(const bf16x8*)(kr + (((l >> 4) + 4) ^ rx) * 8);
      f32x4 a = {0.f, 0.f, 0.f, 0.f};
      a = MFMA16(qf0, kf0, a);
      a = MFMA16(qf1, kf1, a);
      s[kt] = a;
    }

    float inv[4];
#pragma unroll
    for (int r = 0; r < 4; r++) {
      float m = -1e30f;
#pragma unroll
      for (int kt = 0; kt < 32; kt++) m = fmaxf(m, s[kt][r]);
      m = fmaxf(m, __shfl_xor(m, 1));
      m = fmaxf(m, __shfl_xor(m, 2));
      m = fmaxf(m, __shfl_xor(m, 4));
      m = fmaxf(m, __shfl_xor(m, 8));
      float su = 0.f;
#pragma unroll
      for (int kt = 0; kt < 32; kt++) {
        const float pv = expf((s[kt][r] - m) * scale);
        s[kt][r] = pv;
        su += pv;
      }
      su += __shfl_xor(su, 1);
      su += __shfl_xor(su, 2);
      su += __shfl_xor(su, 4);
      su += __shfl_xor(su, 8);
      inv[r] = 1.0f / su;
    }

    if (p == 0) __syncthreads();  // V staged; reached by all waves once

    f32x4 o[4] = {};
#pragma unroll
    for (int cc = 0; cc < 4; ++cc) {
#pragma unroll
      for (int kl = 0; kl < 8; ++kl) {
        const int klocal = kl * 16 + (l & 15);
        const int slot = klocal >> 3;
#pragma unroll
        for (int r = 0; r < 4; ++r) {
          const int q = (l >> 4) * 4 + r;
          Pw[q * 128 + ((slot ^ (q & 7)) << 3) + (klocal & 7)] =
              f2bf(s[cc * 8 + kl][r] * inv[r]);
        }
      }
#pragma unroll
      for (int ks = 0; ks < 4; ++ks) {
        const int q = l & 15;
        const bf16x8 pf =
            *(const bf16x8*)(Pw + q * 128 + (((ks * 4 + (l >> 4)) ^ (q & 7)) << 3));
        const int ci = cc * 16 + ks * 4 + (l >> 4);
#pragma unroll
        for (int j2 = 0; j2 < 4; j2++) {
          const int dr = j2 * 16 + (l & 15);
          const bf16x8 vf = *(const bf16x8*)(Vs + dr * 512 + ((ci ^ (dr & 7)) << 3));
          o[j2] = MFMA16(pf, vf, o[j2]);
        }
      }
    }

#pragma unroll
    for (int j2 = 0; j2 < 4; j2++) {
      const int d = j2 * 16 + (l & 15);
      const int c = h * 64 + d;
      const float w0 = w_lepe[c * 3 + 0], w1 = w_lepe[c * 3 + 1], w2 = w_lepe[c * 3 + 2];
      const float bl = b_lepe[c];
      const int dx = d & 7;
#pragma unroll
      for (int r = 0; r < 4; r++) {
        const int q = (l >> 4) * 4 + r;
        const int n = ql + q;
        float vm1 = 0.f, vp1 = 0.f;
        if (n > 0) {
          const int nn = n - 1;
          vm1 = bf2f(Vs[d * 512 + (((nn >> 3) ^ dx) << 3) + (nn & 7)]);
        }
        const float v0 = bf2f(Vs[d * 512 + (((n >> 3) ^ dx) << 3) + (n & 7)]);
        if (n < 511) {
          const int nn = n + 1;
          vp1 = bf2f(Vs[d * 512 + (((nn >> 3) ^ dx) << 3) + (nn & 7)]);
        }
        const float lepe = vm1 * w0 + v0 * w1 + vp1 * w2 + bl;
        out[((size_t)(bb * N_ + n)) * C_ + c] = o[j2][r] + lepe;
      }
    }
  }
}

// ---------- launcher ----------
extern "C" void kernel_launch(void* const* d_in, const int* in_sizes, int n_in,
                              void* d_out, int out_size, void* d_ws, size_t ws_size,
                              hipStream_t stream) {
  (void)in_sizes; (void)n_in; (void)out_size; (void)ws_size;
  const float* x = (const float*)d_in[0];
  const float* w_qkv = (const float*)d_in[1];
  const float* b_qkv = (const float*)d_in[2];
  const float* w_lepe = (const float*)d_in[3];
  const float* b_lepe = (const float*)d_in[4];
  float* out = (float*)d_out;

  unsigned short* ws = (unsigned short*)d_ws;
  unsigned short* xb = ws;                          // 16777216 el
  unsigned short* wb = xb + 16777216;               // 3145728 el
  unsigned short* Qb = wb + 3145728;                // 16777216 el
  unsigned short* Kb = Qb + 16777216;               // 16777216 el
  unsigned short* Vtb = Kb + 16777216;              // 16777216 el
  float* sin_t = (float*)(Vtb + 16777216);          // 16384 f32
  float* cos_t = sin_t + 16384;                     // 16384 f32

  rope_table_kernel<<<64, 256, 0, stream>>>(sin_t, cos_t);
  cvt_bf16_kernel<<<(16777216 / 8 + 255) / 256, 256, 0, stream>>>(x, xb, 16777216 / 8);
  cvt_bf16_kernel<<<(3145728 / 8 + 255) / 256, 256, 0, stream>>>(w_qkv, wb, 3145728 / 8);
  qkv_gemm_kernel<<<768, 512, 0, stream>>>(xb, wb, b_qkv, Qb, Kb, Vtb, sin_t, cos_t);
  attn_kernel<<<512, 512, 0, stream>>>(Qb, Kb, Vtb, w_lepe, b_lepe, out);
}

// Round 4
// 319.791 us; speedup vs baseline: 1.4603x; 1.0116x over previous
//
#include <hip/hip_runtime.h>
#include <stdint.h>

// ---------- types ----------
typedef __attribute__((ext_vector_type(8))) __bf16 bf16x8;
typedef __attribute__((ext_vector_type(4))) float f32x4;
typedef __attribute__((ext_vector_type(8))) unsigned short u16x8;

#define MFMA16(a, b, c) __builtin_amdgcn_mfma_f32_16x16x32_bf16((a), (b), (c), 0, 0, 0)

__device__ __forceinline__ void glds16(const void* g, void* l) {
  __builtin_amdgcn_global_load_lds(
      (const __attribute__((address_space(1))) void*)(uintptr_t)g,
      (__attribute__((address_space(3))) void*)(uint32_t)(uintptr_t)l,
      16, 0, 0);
}

__device__ __forceinline__ unsigned short f2bf(float f) {
  union { float f; unsigned u; } v; v.f = f;
  unsigned r = v.u + 0x7FFFu + ((v.u >> 16) & 1u);
  return (unsigned short)(r >> 16);
}
__device__ __forceinline__ float bf2f(unsigned short s) {
  union { unsigned u; float f; } v; v.u = ((unsigned)s) << 16;
  return v.f;
}

// ---------- problem constants ----------
#define B_ 32
#define N_ 512
#define C_ 1024
#define H_ 16
#define D_ 64
#define K_ C_                // 1024

// ---------- tiny kernels ----------
__global__ __launch_bounds__(256) void rope_table_kernel(float* __restrict__ sin_t,
                                                         float* __restrict__ cos_t) {
  int idx = blockIdx.x * 256 + threadIdx.x;   // 0..16383 = n*32 + i
  int n = idx >> 5, i = idx & 31;
  float div = expf(-(2.0f * (float)i) * (9.210340371976184f / 64.0f));
  float ang = (float)n * div;
  sin_t[idx] = sinf(ang);
  cos_t[idx] = cosf(ang);
}

__global__ __launch_bounds__(256) void cvt_bf16_kernel(const float* __restrict__ in,
                                                       unsigned short* __restrict__ out,
                                                       int n8) {
  int i = blockIdx.x * blockDim.x + threadIdx.x;
  if (i >= n8) return;
  const float4* p = reinterpret_cast<const float4*>(in) + (size_t)i * 2;
  float4 a = p[0], b = p[1];
  u16x8 o;
  o[0] = f2bf(a.x); o[1] = f2bf(a.y); o[2] = f2bf(a.z); o[3] = f2bf(a.w);
  o[4] = f2bf(b.x); o[5] = f2bf(b.y); o[6] = f2bf(b.z); o[7] = f2bf(b.w);
  *reinterpret_cast<u16x8*>(out + (size_t)i * 8) = o;
}

// ---------- QKV GEMM: 256x256, BK=64, quadrant-phased race-free pipeline ----------
// LDS rows are PERMUTED so each phase's readable region is contiguous:
//   A LDS row rho = qm*128 + wr*64 + (mm*16+lr)  <-> global row m = wr*128 + qm*64 + mm*16+lr
//   B LDS row rho = qn*128 + wc*32 + (jj*16+lr)  <-> global col n = wc*64 + qn*32 + jj*16+lr
// Phase p of tile u: (qm,qn) = (0,0),(0,1),(1,1),(1,0); frags reg-carried so each
// LDS half is ds_read in exactly ONE phase -> staging into it later is race-free.
// Stages: ph1: A1(u+1)->nxt, ph2: B1(u+1)->nxt, ph3: A0(u+2)->cur, ph4: B0(u+2)->cur.
// Boundary: vmcnt(4) (tile u+1 = oldest 8 loads; 2 halves in flight) + barrier.
#define STAGE_AH(bi, uu, qm)                                                      \
  do {                                                                            \
    glds16(aP0 + (size_t)(qm) * (64 * K_) + (uu) * 64, &lds[bi][(qm)*8192 + t * 8]); \
    glds16(aP1 + (size_t)(qm) * (64 * K_) + (uu) * 64,                            \
           &lds[bi][(qm)*8192 + 4096 + t * 8]);                                   \
  } while (0)
#define STAGE_BH(bi, uu, qn)                                                      \
  do {                                                                            \
    glds16(bP0 + (size_t)(qn) * (32 * K_) + (uu) * 64,                            \
           &lds[bi][16384 + (qn)*8192 + t * 8]);                                  \
    glds16(bP1 + (size_t)(qn) * (32 * K_) + (uu) * 64,                            \
           &lds[bi][16384 + (qn)*8192 + 4096 + t * 8]);                           \
  } while (0)

__global__ __launch_bounds__(512, 2) void qkv_gemm_kernel(
    const unsigned short* __restrict__ xb, const unsigned short* __restrict__ wb,
    const float* __restrict__ bias,
    unsigned short* __restrict__ Qb, unsigned short* __restrict__ Kb,
    unsigned short* __restrict__ Vtb,
    const float* __restrict__ sin_t, const float* __restrict__ cos_t) {
  __shared__ unsigned short lds[2][32768];  // 128 KB
  const int t = threadIdx.x;
  const int wv = t >> 6, l = t & 63;
  const int wr = wv >> 2, wc = wv & 3;   // 2 x 4 waves, wave tile 128x64
  const int lq = l >> 4, lr = l & 15, sx = l & 7;

  // XCD-chunked bijective swizzle (768 = 8 * 96)
  const int bid = (blockIdx.x & 7) * 96 + (blockIdx.x >> 3);
  const int mBlk = bid / 12, nBlk = bid % 12;
  const int m0 = mBlk * 256, n0 = nBlk * 256;

  // staging source pointers (global chunk pre-swizzled; LDS dest linear)
  const int rl = t >> 3;                       // 0..63
  const int cw = ((t & 7) ^ (rl & 7)) * 8;     // swizzled source chunk (halfwords)
  const unsigned short* aP0 = xb + (size_t)(m0 + rl) * K_ + cw;
  const unsigned short* aP1 = xb + (size_t)(m0 + 128 + rl) * K_ + cw;
  const unsigned short* bP0 = wb + (size_t)(n0 + ((rl >> 5) << 6) + (rl & 31)) * K_ + cw;
  const unsigned short* bP1 = wb + (size_t)(n0 + 128 + ((rl >> 5) << 6) + (rl & 31)) * K_ + cw;

  // fragment read offsets (halfwords); phase adds qm*8192 / qn*8192 and mm/jj*1024
  int aoff[2], boff[2];
#pragma unroll
  for (int s = 0; s < 2; ++s) {
    const int ch = ((s * 4 + lq) ^ sx) * 8;
    aoff[s] = (wr * 64 + lr) * 64 + ch;
    boff[s] = 16384 + (wc * 32 + lr) * 64 + ch;
  }

  f32x4 acc[8][4] = {};

  // prologue: tile 0 (4 halves) + first 2 halves of tile 1 (issue order = retire order)
  STAGE_AH(0, 0, 0); STAGE_BH(0, 0, 0); STAGE_AH(0, 0, 1); STAGE_BH(0, 0, 1);
  STAGE_AH(1, 1, 0); STAGE_BH(1, 1, 0);

  for (int u = 0; u < 16; ++u) {
    const int cur = u & 1, nxt = cur ^ 1;
    const unsigned short* Lc = &lds[cur][0];
    if (u == 15) asm volatile("s_waitcnt vmcnt(0)" ::: "memory");
    else         asm volatile("s_waitcnt vmcnt(4)" ::: "memory");
    __builtin_amdgcn_s_barrier();   // all waves' tile-u stages visible

    bf16x8 afr[4][2], bf0[2][2], bf1[2][2];

    // ---- ph1 (qm0,qn0): read A-half0 (8) + B-half0 (4); stage A-half1(u+1)->nxt
#pragma unroll
    for (int mm = 0; mm < 4; ++mm)
#pragma unroll
      for (int s = 0; s < 2; ++s)
        afr[mm][s] = *(const bf16x8*)(Lc + aoff[s] + mm * 1024);
#pragma unroll
    for (int jj = 0; jj < 2; ++jj)
#pragma unroll
      for (int s = 0; s < 2; ++s)
        bf0[jj][s] = *(const bf16x8*)(Lc + boff[s] + jj * 1024);
    if (u + 1 < 16) STAGE_AH(nxt, u + 1, 1);
    __builtin_amdgcn_s_barrier();
    asm volatile("s_waitcnt lgkmcnt(0)" ::: "memory");
    __builtin_amdgcn_s_setprio(1);
#pragma unroll
    for (int mm = 0; mm < 4; ++mm)
#pragma unroll
      for (int jj = 0; jj < 2; ++jj)
#pragma unroll
        for (int s = 0; s < 2; ++s)
          acc[mm][jj] = MFMA16(afr[mm][s], bf0[jj][s], acc[mm][jj]);
    __builtin_amdgcn_s_setprio(0);

    // ---- ph2 (qm0,qn1): read B-half1 (4); stage B-half1(u+1)->nxt
#pragma unroll
    for (int jj = 0; jj < 2; ++jj)
#pragma unroll
      for (int s = 0; s < 2; ++s)
        bf1[jj][s] = *(const bf16x8*)(Lc + boff[s] + 8192 + jj * 1024);
    if (u + 1 < 16) STAGE_BH(nxt, u + 1, 1);
    __builtin_amdgcn_s_barrier();
    asm volatile("s_waitcnt lgkmcnt(0)" ::: "memory");
    __builtin_amdgcn_s_setprio(1);
#pragma unroll
    for (int mm = 0; mm < 4; ++mm)
#pragma unroll
      for (int jj = 0; jj < 2; ++jj)
#pragma unroll
        for (int s = 0; s < 2; ++s)
          acc[mm][2 + jj] = MFMA16(afr[mm][s], bf1[jj][s], acc[mm][2 + jj]);
    __builtin_amdgcn_s_setprio(0);

    // ---- ph3 (qm1,qn1): read A-half1 (8); stage A-half0(u+2)->cur (readers done ph1)
#pragma unroll
    for (int mm = 0; mm < 4; ++mm)
#pragma unroll
      for (int s = 0; s < 2; ++s)
        afr[mm][s] = *(const bf16x8*)(Lc + aoff[s] + 8192 + mm * 1024);
    if (u + 2 < 16) STAGE_AH(cur, u + 2, 0);
    __builtin_amdgcn_s_barrier();
    asm volatile("s_waitcnt lgkmcnt(0)" ::: "memory");
    __builtin_amdgcn_s_setprio(1);
#pragma unroll
    for (int mm = 0; mm < 4; ++mm)
#pragma unroll
      for (int jj = 0; jj < 2; ++jj)
#pragma unroll
        for (int s = 0; s < 2; ++s)
          acc[4 + mm][2 + jj] = MFMA16(afr[mm][s], bf1[jj][s], acc[4 + mm][2 + jj]);
    __builtin_amdgcn_s_setprio(0);

    // ---- ph4 (qm1,qn0): no ds_reads (regs carried); stage B-half0(u+2)->cur
    if (u + 2 < 16) STAGE_BH(cur, u + 2, 0);
    __builtin_amdgcn_s_barrier();
    __builtin_amdgcn_s_setprio(1);
#pragma unroll
    for (int mm = 0; mm < 4; ++mm)
#pragma unroll
      for (int jj = 0; jj < 2; ++jj)
#pragma unroll
        for (int s = 0; s < 2; ++s)
          acc[4 + mm][jj] = MFMA16(afr[mm][s], bf0[jj][s], acc[4 + mm][jj]);
    __builtin_amdgcn_s_setprio(0);
  }

  // ---- fused epilogue: bias + (elu+1, rope -> Qb/Kb) or (V -> Vtb transposed) ----
#pragma unroll
  for (int mf = 0; mf < 8; ++mf) {
#pragma unroll
    for (int j = 0; j < 4; ++j) {
      const int ncol = n0 + wc * 64 + j * 16 + lr;
      const int sel = ncol >> 10;
      const int hh = (ncol & 1023) >> 6;
      const int d = ncol & 63;
      const float bias_v = bias[ncol];
#pragma unroll
      for (int r = 0; r < 4; ++r) {
        const int m = m0 + wr * 128 + mf * 16 + lq * 4 + r;
        const int bb = m >> 9, n = m & 511;
        const float val = acc[mf][j][r] + bias_v;
        if (sel == 2) {
          Vtb[((size_t)(bb * H_ + hh) * D_ + d) * N_ + n] = f2bf(val);
        } else {
          const float e = val > 0.f ? val + 1.f : expf(val);  // elu+1
          const float partner = __shfl_xor(e, 1);
          const int ip = d >> 1;
          const float sv = sin_t[n * 32 + ip], cv = cos_t[n * 32 + ip];
          const float o = (d & 1) ? (partner * sv + e * cv) : (e * cv - partner * sv);
          unsigned short* dst = (sel == 0) ? Qb : Kb;
          dst[((size_t)(bb * H_ + hh) * N_ + n) * D_ + d] = f2bf(o);
        }
      }
    }
  }
}

// ---------- attention + lepe : one block per (b,h) ----------
__global__ __launch_bounds__(512, 2) void attn_kernel(
    const unsigned short* __restrict__ Qb, const unsigned short* __restrict__ Kb,
    const unsigned short* __restrict__ Vtb,
    const float* __restrict__ w_lepe, const float* __restrict__ b_lepe,
    float* __restrict__ out) {
  __shared__ unsigned short Ks[512 * 64];
  __shared__ unsigned short Vs[64 * 512];
  __shared__ unsigned short Pb[8 * 16 * 128];
  const int t = threadIdx.x, wv = t >> 6, l = t & 63;
  const int bh = blockIdx.x;           // 0..511
  const int bb = bh >> 4, h = bh & 15;
  const size_t base = (size_t)bh * (N_ * D_);

  {
    const int row8 = t >> 3, ch = t & 7;
#pragma unroll
    for (int c = 0; c < 8; ++c) {
      const int r = c * 64 + row8;
      const int sch = ch ^ (r & 7);
      glds16(Kb + base + (size_t)r * D_ + sch * 8, Ks + c * 4096 + t * 8);
    }
  }
  {
    const int ch = t & 63;
#pragma unroll
    for (int c = 0; c < 8; ++c) {
      const int d = c * 8 + wv;
      const int sch = ch ^ (d & 7);
      glds16(Vtb + base + (size_t)d * N_ + sch * 8, Vs + c * 4096 + t * 8);
    }
  }

  asm volatile("s_waitcnt vmcnt(8)" ::: "memory");
  __builtin_amdgcn_s_barrier();

  const float scale = 0.125f;  // 1/sqrt(64)
  unsigned short* Pw = Pb + wv * 2048;

  for (int p = 0; p < 4; ++p) {
    const int ql = wv * 64 + p * 16;
    const bf16x8 qf0 = *(const bf16x8*)(Qb + base + (size_t)(ql + (l & 15)) * D_ + (l >> 4) * 8);
    const bf16x8 qf1 = *(const bf16x8*)(Qb + base + (size_t)(ql + (l & 15)) * D_ + 32 + (l >> 4) * 8);

    f32x4 s[32];
#pragma unroll
    for (int kt = 0; kt < 32; ++kt) {
      const int r = kt * 16 + (l & 15);
      const int rx = r & 7;
      const unsigned short* kr = Ks + r * 64;
      const bf16x8 kf0 = *(const bf16x8*)(kr + (((l >> 4)) ^ rx) * 8);
      const bf16x8 kf1 = *(const bf16x8*)(kr + (((l >> 4) + 4) ^ rx) * 8);
      f32x4 a = {0.f, 0.f, 0.f, 0.f};
      a = MFMA16(qf0, kf0, a);
      a = MFMA16(qf1, kf1, a);
      s[kt] = a;
    }

    float inv[4];
#pragma unroll
    for (int r = 0; r < 4; r++) {
      float m = -1e30f;
#pragma unroll
      for (int kt = 0; kt < 32; kt++) m = fmaxf(m, s[kt][r]);
      m = fmaxf(m, __shfl_xor(m, 1));
      m = fmaxf(m, __shfl_xor(m, 2));
      m = fmaxf(m, __shfl_xor(m, 4));
      m = fmaxf(m, __shfl_xor(m, 8));
      float su = 0.f;
#pragma unroll
      for (int kt = 0; kt < 32; kt++) {
        const float pv = expf((s[kt][r] - m) * scale);
        s[kt][r] = pv;
        su += pv;
      }
      su += __shfl_xor(su, 1);
      su += __shfl_xor(su, 2);
      su += __shfl_xor(su, 4);
      su += __shfl_xor(su, 8);
      inv[r] = 1.0f / su;
    }

    if (p == 0) __syncthreads();  // V staged; reached by all waves once

    f32x4 o[4] = {};
#pragma unroll
    for (int cc = 0; cc < 4; ++cc) {
#pragma unroll
      for (int kl = 0; kl < 8; ++kl) {
        const int klocal = kl * 16 + (l & 15);
        const int slot = klocal >> 3;
#pragma unroll
        for (int r = 0; r < 4; ++r) {
          const int q = (l >> 4) * 4 + r;
          Pw[q * 128 + ((slot ^ (q & 7)) << 3) + (klocal & 7)] =
              f2bf(s[cc * 8 + kl][r] * inv[r]);
        }
      }
#pragma unroll
      for (int ks = 0; ks < 4; ++ks) {
        const int q = l & 15;
        const bf16x8 pf =
            *(const bf16x8*)(Pw + q * 128 + (((ks * 4 + (l >> 4)) ^ (q & 7)) << 3));
        const int ci = cc * 16 + ks * 4 + (l >> 4);
#pragma unroll
        for (int j2 = 0; j2 < 4; j2++) {
          const int dr = j2 * 16 + (l & 15);
          const bf16x8 vf = *(const bf16x8*)(Vs + dr * 512 + ((ci ^ (dr & 7)) << 3));
          o[j2] = MFMA16(pf, vf, o[j2]);
        }
      }
    }

#pragma unroll
    for (int j2 = 0; j2 < 4; j2++) {
      const int d = j2 * 16 + (l & 15);
      const int c = h * 64 + d;
      const float w0 = w_lepe[c * 3 + 0], w1 = w_lepe[c * 3 + 1], w2 = w_lepe[c * 3 + 2];
      const float bl = b_lepe[c];
      const int dx = d & 7;
#pragma unroll
      for (int r = 0; r < 4; r++) {
        const int q = (l >> 4) * 4 + r;
        const int n = ql + q;
        float vm1 = 0.f, vp1 = 0.f;
        if (n > 0) {
          const int nn = n - 1;
          vm1 = bf2f(Vs[d * 512 + (((nn >> 3) ^ dx) << 3) + (nn & 7)]);
        }
        const float v0 = bf2f(Vs[d * 512 + (((n >> 3) ^ dx) << 3) + (n & 7)]);
        if (n < 511) {
          const int nn = n + 1;
          vp1 = bf2f(Vs[d * 512 + (((nn >> 3) ^ dx) << 3) + (nn & 7)]);
        }
        const float lepe = vm1 * w0 + v0 * w1 + vp1 * w2 + bl;
        out[((size_t)(bb * N_ + n)) * C_ + c] = o[j2][r] + lepe;
      }
    }
  }
}

// ---------- launcher ----------
extern "C" void kernel_launch(void* const* d_in, const int* in_sizes, int n_in,
                              void* d_out, int out_size, void* d_ws, size_t ws_size,
                              hipStream_t stream) {
  (void)in_sizes; (void)n_in; (void)out_size; (void)ws_size;
  const float* x = (const float*)d_in[0];
  const float* w_qkv = (const float*)d_in[1];
  const float* b_qkv = (const float*)d_in[2];
  const float* w_lepe = (const float*)d_in[3];
  const float* b_lepe = (const float*)d_in[4];
  float* out = (float*)d_out;

  unsigned short* ws = (unsigned short*)d_ws;
  unsigned short* xb = ws;                          // 16777216 el
  unsigned short* wb = xb + 16777216;               // 3145728 el
  unsigned short* Qb = wb + 3145728;                // 16777216 el
  unsigned short* Kb = Qb + 16777216;               // 16777216 el
  unsigned short* Vtb = Kb + 16777216;              // 16777216 el
  float* sin_t = (float*)(Vtb + 16777216);          // 16384 f32
  float* cos_t = sin_t + 16384;                     // 16384 f32

  rope_table_kernel<<<64, 256, 0, stream>>>(sin_t, cos_t);
  cvt_bf16_kernel<<<(16777216 / 8 + 255) / 256, 256, 0, stream>>>(x, xb, 16777216 / 8);
  cvt_bf16_kernel<<<(3145728 / 8 + 255) / 256, 256, 0, stream>>>(w_qkv, wb, 3145728 / 8);
  qkv_gemm_kernel<<<768, 512, 0, stream>>>(xb, wb, b_qkv, Qb, Kb, Vtb, sin_t, cos_t);
  attn_kernel<<<512, 512, 0, stream>>>(Qb, Kb, Vtb, w_lepe, b_lepe, out);
}